// Round 20
// baseline (252.216 us; speedup 1.0000x reference)
//
#include <hip/hip_runtime.h>
#include <hip/hip_bf16.h>

#define N_TOK 65536
#define KCB   512
#define DIM   64
#define TPB   32    // tokens per block
#define CAP   16    // per-token candidate capacity (overflow -> full rescan)

typedef __attribute__((ext_vector_type(4)))  float f32x4;
typedef __attribute__((ext_vector_type(8)))  short s16x8;
typedef __attribute__((ext_vector_type(16))) float f32x16;
typedef unsigned long long u64;

__device__ __forceinline__ unsigned bf16rne(float f) {
  unsigned u = __float_as_uint(f);
  return (u + 0x7FFFu + ((u >> 16) & 1u)) >> 16;   // round-to-nearest-even
}
__device__ __forceinline__ unsigned bf2(float lo, float hi) {
  return bf16rne(lo) | (bf16rne(hi) << 16);
}
// Monotone f32->u32: unsigned compare == float compare (total order).
__device__ __forceinline__ unsigned mono(float f) {
  unsigned u = __float_as_uint(f);
  return u ^ ((unsigned)((int)u >> 31) | 0x80000000u);
}
__device__ __forceinline__ u64 u64min(u64 a, u64 b) { return a < b ? a : b; }

// Exact f32 score of row k for an 8-lane group's token (INLINE — no ABI).
__device__ __forceinline__ u64 group_score8(
    const float* __restrict__ cb, const float* __restrict__ erow,
    const float* __restrict__ csql, int k, int sub) {
  const float4* c4 = reinterpret_cast<const float4*>(cb + (size_t)k * DIM + sub * 8);
  const float4* e4 = reinterpret_cast<const float4*>(erow);
  const float4 c0 = c4[0], c1 = c4[1], e0 = e4[0], e1 = e4[1];
  float s0 = 0.f, s1 = 0.f;
  s0 = fmaf(c0.x, e0.x, s0); s1 = fmaf(c0.y, e0.y, s1);
  s0 = fmaf(c0.z, e0.z, s0); s1 = fmaf(c0.w, e0.w, s1);
  s0 = fmaf(c1.x, e1.x, s0); s1 = fmaf(c1.y, e1.y, s1);
  s0 = fmaf(c1.z, e1.z, s0); s1 = fmaf(c1.w, e1.w, s1);
  float p = s0 + s1;
  p += __shfl_xor(p, 1);
  p += __shfl_xor(p, 2);
  p += __shfl_xor(p, 4);
  const float S = fmaf(-2.f, p, csql[k]);
  return ((u64)mono(S) << 32) | (unsigned)k;
}

// Prep: codebook -> FRAGMENT-MAJOR bf16 layout + csq.
__global__ __launch_bounds__(256) void vq_prep_kernel(
    const float* __restrict__ cb, uint4* __restrict__ cb_frag,
    float* __restrict__ csqg) {
  const int gid = blockIdx.x * 256 + threadIdx.x;
  if (gid < 4096) {                       // 16 RT x 4 s x 64 lanes
    const int f = gid >> 6, lane = gid & 63;
    const int RT = f >> 2, s = f & 3;
    const int row = RT * 32 + (lane & 31);
    const float4* src =
        reinterpret_cast<const float4*>(cb + (size_t)row * DIM + s * 16 + (lane >> 5) * 8);
    const float4 a = src[0], b = src[1];
    cb_frag[gid] = make_uint4(bf2(a.x, a.y), bf2(a.z, a.w), bf2(b.x, b.y), bf2(b.z, b.w));
  } else if (gid < 4096 + KCB) {
    const int k = gid - 4096;
    const float4* r4 = reinterpret_cast<const float4*>(cb + (size_t)k * DIM);
    float s = 0.f;
#pragma unroll
    for (int i = 0; i < 16; ++i) {
      float4 c = r4[i];
      s = fmaf(c.x, c.x, s); s = fmaf(c.y, c.y, s);
      s = fmaf(c.z, c.z, s); s = fmaf(c.w, c.w, s);
    }
    csqg[k] = s;
  }
}

// SINGLE-PASS certified argmin + fused gather.
// Round-20 delta vs r16: candidates are collected ONLINE in pass A against
// the per-lane RUNNING min + marg. Superset property: running >= final >=
// block min, so every score within marg of the block min is collected; the
// true argmin always qualifies when processed. Stale extras are filtered by
// phase C's exact rescore. Pass B (16 L2 fragment loads + 16 MFMAs), the
// cross-wave m_red reduce, thr section, and one barrier are all DELETED.
// Accs still die per-tile (no r17 register pressure); occupancy stays 6.
__global__ __launch_bounds__(256, 6) void vq_argmin_kernel(
    const float* __restrict__ cb,
    const float* __restrict__ emb,
    const uint4* __restrict__ cb_frag,
    const float* __restrict__ csqg,
    float* __restrict__ out) {
  __shared__ float ef32[TPB * DIM];      // 8 KB f32 tokens
  __shared__ char  etile[TPB * 128];     // 4 KB swizzled bf16 tokens
  __shared__ float csq_l[KCB];           // 2 KB
  __shared__ float esq_p[256];           // 1 KB (8 partials per token)
  __shared__ int   cnt[TPB];
  __shared__ short list[TPB][CAP];
  __shared__ int   sel[TPB];

  const int tid  = threadIdx.x;
  const int lane = tid & 63;
  const int w    = tid >> 6;
  const int col  = lane & 31;            // token within block
  const int half = lane >> 5;
  const int blk  = blockIdx.x;

  if (tid < TPB) cnt[tid] = 0;

  // ---- stage 32 tokens: 8 f32/thread -> {f32 LDS, RNE-bf16 swizzled} ----
  {
    const float4* ep4 = reinterpret_cast<const float4*>(emb + (size_t)blk * TPB * DIM);
    const float4 v0 = ep4[tid * 2 + 0], v1 = ep4[tid * 2 + 1];
    float ss = 0.f;
    ss = fmaf(v0.x, v0.x, ss); ss = fmaf(v0.y, v0.y, ss);
    ss = fmaf(v0.z, v0.z, ss); ss = fmaf(v0.w, v0.w, ss);
    ss = fmaf(v1.x, v1.x, ss); ss = fmaf(v1.y, v1.y, ss);
    ss = fmaf(v1.z, v1.z, ss); ss = fmaf(v1.w, v1.w, ss);
    esq_p[tid] = ss;
    float4* ed = reinterpret_cast<float4*>(ef32);
    ed[tid * 2 + 0] = v0;
    ed[tid * 2 + 1] = v1;
    const int tok = tid >> 3, c0 = tid & 7;        // 16B bf16 chunk c0
    const int a0 = tok * 128 + ((16 * c0) ^ ((tok & 7) << 4));
    *reinterpret_cast<uint4*>(etile + a0) =
        make_uint4(bf2(v0.x, v0.y), bf2(v0.z, v0.w), bf2(v1.x, v1.y), bf2(v1.z, v1.w));
  }
  if (tid < 128)
    reinterpret_cast<float4*>(csq_l)[tid] = reinterpret_cast<const float4*>(csqg)[tid];
  __syncthreads();                                          // barrier 1

  // ---- B-fragment preload (4 ds_read_b128 per lane) ----
  s16x8 Bf[4];
#pragma unroll
  for (int s = 0; s < 4; ++s) {
    const int c = 2 * s + half;
    const int a = col * 128 + ((16 * c) ^ ((col & 7) << 4));
    Bf[s] = *reinterpret_cast<const s16x8*>(etile + a);
  }

  // per-lane margin for its token: 2*B_t bound (certified rounds 6-18)
  float marg;
  {
    const float esq = ((esq_p[col * 8 + 0] + esq_p[col * 8 + 1]) +
                       (esq_p[col * 8 + 2] + esq_p[col * 8 + 3])) +
                      ((esq_p[col * 8 + 4] + esq_p[col * 8 + 5]) +
                       (esq_p[col * 8 + 6] + esq_p[col * 8 + 7]));
    marg = 0.0328f * sqrtf(esq) + 2e-4f;
  }

  const int rowbase = w * 128;
  const s16x8* frag = reinterpret_cast<const s16x8*>(cb_frag);

  // ---- Pass A (only pass): MFMA -> scores; ONLINE candidate collection ----
  float m = 3.4e38f;
#pragma unroll
  for (int rt = 0; rt < 4; ++rt) {
    f32x16 a0 = {};
#pragma unroll
    for (int s = 0; s < 4; ++s) {
      const s16x8 Af = frag[((w * 4 + rt) * 4 + s) * 64 + lane];  // coalesced 1KB
      a0 = __builtin_amdgcn_mfma_f32_32x32x16_bf16(Af, Bf[s], a0, 0, 0, 0);
    }
    const int rb = rowbase + rt * 32 + 4 * half;
    float S[16];
    float g = 3.4e38f;
#pragma unroll
    for (int gq = 0; gq < 4; ++gq) {
      const float4 cs = *reinterpret_cast<const float4*>(&csq_l[rb + 8 * gq]);
#pragma unroll
      for (int e = 0; e < 4; ++e) {
        const float c = (e == 0) ? cs.x : (e == 1) ? cs.y : (e == 2) ? cs.z : cs.w;
        const float Sv = fmaf(-2.f, a0[gq * 4 + e], c);
        S[gq * 4 + e] = Sv;
        g = fminf(g, Sv);
      }
    }
    m = fminf(m, g);                      // running min INCLUDING this tile
    const float thr = m + marg;
#pragma unroll
    for (int gq = 0; gq < 4; ++gq)
#pragma unroll
      for (int e = 0; e < 4; ++e)
        if (S[gq * 4 + e] <= thr) {
          const int p = atomicAdd(&cnt[col], 1);
          if (p < CAP) list[col][p] = (short)(rb + 8 * gq + e);
        }
  }
  __syncthreads();                                          // barrier 2

  // ---- Phase C: 8 lanes per token, inline exact-f32 rescore ----
  {
    const int t = tid >> 3, sub = tid & 7;
    const int nc = cnt[t];
    const float* erow = ef32 + t * DIM + sub * 8;
    u64 bb = ~0ull;
    if (nc <= CAP) {
      for (int i = 0; i < nc; ++i)
        bb = u64min(bb, group_score8(cb, erow, csq_l, list[t][i], sub));
    } else {
      // overflow (adversarial data only): full exact scan, still correct
      for (int k = 0; k < KCB; ++k)
        bb = u64min(bb, group_score8(cb, erow, csq_l, k, sub));
    }
    if (sub == 0) {
      const int idx = (int)(unsigned)(bb & 0xFFFFFFFFull);
      sel[t] = idx;
      __builtin_nontemporal_store(
          (float)idx, &out[(size_t)2 * N_TOK * DIM + blk * TPB + t]);
    }
  }
  __syncthreads();                                          // barrier 3

  // ---- Phase D: fused gather-write of both quantized sections (NT) ----
  {
    const float4* cb4 = reinterpret_cast<const float4*>(cb);
    f32x4* out4 = reinterpret_cast<f32x4*>(out);
#pragma unroll
    for (int mm = 0; mm < 2; ++mm) {
      const int i = tid + 256 * mm;
      const int t = i >> 4, j = i & 15;
      const float4 v = cb4[sel[t] * (DIM / 4) + j];
      const f32x4 vv = {v.x, v.y, v.z, v.w};
      const size_t g = (size_t)(blk * TPB + t) * (DIM / 4) + j;
      __builtin_nontemporal_store(vv, &out4[g]);
      __builtin_nontemporal_store(vv, &out4[(size_t)N_TOK * (DIM / 4) + g]);
    }
  }
}

extern "C" void kernel_launch(void* const* d_in, const int* in_sizes, int n_in,
                              void* d_out, int out_size, void* d_ws, size_t ws_size,
                              hipStream_t stream) {
  const float* cb  = (const float*)d_in[0];   // (512, 64) f32
  const float* emb = (const float*)d_in[1];   // (65536, 1, 64) f32
  float* out = (float*)d_out;
  uint4* cb_frag = (uint4*)d_ws;                               // 64 KB fragment-major bf16
  float* csqg = (float*)((char*)d_ws + (size_t)KCB * DIM * 2); // 2 KB csq

  vq_prep_kernel<<<18, 256, 0, stream>>>(cb, cb_frag, csqg);
  vq_argmin_kernel<<<N_TOK / TPB, 256, 0, stream>>>(cb, emb, cb_frag, csqg, out);
}

// Round 21
// 27.011 us; speedup vs baseline: 9.3375x; 9.3375x over previous
//
#include <hip/hip_runtime.h>
#include <hip/hip_bf16.h>

#define N_TOK 65536
#define KCB   512
#define DIM   64
#define TPB   32    // tokens per block
#define CAP   16    // per-token candidate capacity (overflow -> full rescan)

typedef __attribute__((ext_vector_type(4)))  float f32x4;
typedef __attribute__((ext_vector_type(8)))  short s16x8;
typedef __attribute__((ext_vector_type(16))) float f32x16;
typedef unsigned long long u64;

__device__ __forceinline__ unsigned bf16rne(float f) {
  unsigned u = __float_as_uint(f);
  return (u + 0x7FFFu + ((u >> 16) & 1u)) >> 16;   // round-to-nearest-even
}
__device__ __forceinline__ unsigned bf2(float lo, float hi) {
  return bf16rne(lo) | (bf16rne(hi) << 16);
}
// Monotone f32->u32: unsigned compare == float compare (total order).
__device__ __forceinline__ unsigned mono(float f) {
  unsigned u = __float_as_uint(f);
  return u ^ ((unsigned)((int)u >> 31) | 0x80000000u);
}
__device__ __forceinline__ u64 u64min(u64 a, u64 b) { return a < b ? a : b; }

// Exact f32 score of row k for an 8-lane group's token (INLINE — no ABI).
// shfl_xor chain -> reduced score (and thus the packed result) is UNIFORM
// across the 8-lane group.
__device__ __forceinline__ u64 group_score8(
    const float* __restrict__ cb, const float* __restrict__ erow,
    const float* __restrict__ csql, int k, int sub) {
  const float4* c4 = reinterpret_cast<const float4*>(cb + (size_t)k * DIM + sub * 8);
  const float4* e4 = reinterpret_cast<const float4*>(erow);
  const float4 c0 = c4[0], c1 = c4[1], e0 = e4[0], e1 = e4[1];
  float s0 = 0.f, s1 = 0.f;
  s0 = fmaf(c0.x, e0.x, s0); s1 = fmaf(c0.y, e0.y, s1);
  s0 = fmaf(c0.z, e0.z, s0); s1 = fmaf(c0.w, e0.w, s1);
  s0 = fmaf(c1.x, e1.x, s0); s1 = fmaf(c1.y, e1.y, s1);
  s0 = fmaf(c1.z, e1.z, s0); s1 = fmaf(c1.w, e1.w, s1);
  float p = s0 + s1;
  p += __shfl_xor(p, 1);
  p += __shfl_xor(p, 2);
  p += __shfl_xor(p, 4);
  const float S = fmaf(-2.f, p, csql[k]);
  return ((u64)mono(S) << 32) | (unsigned)k;
}

// Prep: codebook -> FRAGMENT-MAJOR bf16 layout + csq.
__global__ __launch_bounds__(256) void vq_prep_kernel(
    const float* __restrict__ cb, uint4* __restrict__ cb_frag,
    float* __restrict__ csqg) {
  const int gid = blockIdx.x * 256 + threadIdx.x;
  if (gid < 4096) {                       // 16 RT x 4 s x 64 lanes
    const int f = gid >> 6, lane = gid & 63;
    const int RT = f >> 2, s = f & 3;
    const int row = RT * 32 + (lane & 31);
    const float4* src =
        reinterpret_cast<const float4*>(cb + (size_t)row * DIM + s * 16 + (lane >> 5) * 8);
    const float4 a = src[0], b = src[1];
    cb_frag[gid] = make_uint4(bf2(a.x, a.y), bf2(a.z, a.w), bf2(b.x, b.y), bf2(b.z, b.w));
  } else if (gid < 4096 + KCB) {
    const int k = gid - 4096;
    const float4* r4 = reinterpret_cast<const float4*>(cb + (size_t)k * DIM);
    float s = 0.f;
#pragma unroll
    for (int i = 0; i < 16; ++i) {
      float4 c = r4[i];
      s = fmaf(c.x, c.x, s); s = fmaf(c.y, c.y, s);
      s = fmaf(c.z, c.z, s); s = fmaf(c.w, c.w, s);
    }
    csqg[k] = s;
  }
}

// Fused certified argmin + gather (round-16 structure, best: 27.3us).
// Round-21 delta: phase D fused INTO phase C — group_score8's reduced
// result is uniform across each 8-lane group, so the group writes its
// token's two output sections directly (2 float4/lane/section, wave-
// coalesced). Deletes barrier 4 + sel[] LDS round-trip; output writes
// start per-group as soon as each token resolves.
__global__ __launch_bounds__(256, 6) void vq_argmin_kernel(
    const float* __restrict__ cb,
    const float* __restrict__ emb,
    const uint4* __restrict__ cb_frag,
    const float* __restrict__ csqg,
    float* __restrict__ out) {
  __shared__ float ef32[TPB * DIM];      // 8 KB f32 tokens
  __shared__ char  etile[TPB * 128];     // 4 KB swizzled bf16 tokens
  __shared__ float csq_l[KCB];           // 2 KB
  __shared__ float esq_p[256];           // 1 KB (8 partials per token)
  __shared__ float m_red[4][TPB];
  __shared__ int   cnt[TPB];
  __shared__ short list[TPB][CAP];

  const int tid  = threadIdx.x;
  const int lane = tid & 63;
  const int w    = tid >> 6;
  const int col  = lane & 31;            // token within block
  const int half = lane >> 5;
  const int blk  = blockIdx.x;

  if (tid < TPB) cnt[tid] = 0;

  // ---- stage 32 tokens: 8 f32/thread -> {f32 LDS, RNE-bf16 swizzled} ----
  {
    const float4* ep4 = reinterpret_cast<const float4*>(emb + (size_t)blk * TPB * DIM);
    const float4 v0 = ep4[tid * 2 + 0], v1 = ep4[tid * 2 + 1];
    float ss = 0.f;
    ss = fmaf(v0.x, v0.x, ss); ss = fmaf(v0.y, v0.y, ss);
    ss = fmaf(v0.z, v0.z, ss); ss = fmaf(v0.w, v0.w, ss);
    ss = fmaf(v1.x, v1.x, ss); ss = fmaf(v1.y, v1.y, ss);
    ss = fmaf(v1.z, v1.z, ss); ss = fmaf(v1.w, v1.w, ss);
    esq_p[tid] = ss;
    float4* ed = reinterpret_cast<float4*>(ef32);
    ed[tid * 2 + 0] = v0;
    ed[tid * 2 + 1] = v1;
    const int tok = tid >> 3, c0 = tid & 7;        // 16B bf16 chunk c0
    const int a0 = tok * 128 + ((16 * c0) ^ ((tok & 7) << 4));
    *reinterpret_cast<uint4*>(etile + a0) =
        make_uint4(bf2(v0.x, v0.y), bf2(v0.z, v0.w), bf2(v1.x, v1.y), bf2(v1.z, v1.w));
  }
  if (tid < 128)
    reinterpret_cast<float4*>(csq_l)[tid] = reinterpret_cast<const float4*>(csqg)[tid];
  __syncthreads();                                          // barrier 1

  // ---- B-fragment preload (4 ds_read_b128 per lane) ----
  s16x8 Bf[4];
#pragma unroll
  for (int s = 0; s < 4; ++s) {
    const int c = 2 * s + half;
    const int a = col * 128 + ((16 * c) ^ ((col & 7) << 4));
    Bf[s] = *reinterpret_cast<const s16x8*>(etile + a);
  }

  const int rowbase = w * 128;
  const s16x8* frag = reinterpret_cast<const s16x8*>(cb_frag);

  // ---- Pass A: MFMA -> per-row-tile mins + running min (16 accs live) ----
  float gmin[4];
  float m = 3.4e38f;
#pragma unroll
  for (int rt = 0; rt < 4; ++rt) {
    f32x16 a0 = {};
#pragma unroll
    for (int s = 0; s < 4; ++s) {
      const s16x8 Af = frag[((w * 4 + rt) * 4 + s) * 64 + lane];  // coalesced 1KB
      a0 = __builtin_amdgcn_mfma_f32_32x32x16_bf16(Af, Bf[s], a0, 0, 0, 0);
    }
    const int rb = rowbase + rt * 32 + 4 * half;
    float g = 3.4e38f;
#pragma unroll
    for (int gq = 0; gq < 4; ++gq) {
      const float4 cs = *reinterpret_cast<const float4*>(&csq_l[rb + 8 * gq]);
#pragma unroll
      for (int e = 0; e < 4; ++e) {
        const float c = (e == 0) ? cs.x : (e == 1) ? cs.y : (e == 2) ? cs.z : cs.w;
        g = fminf(g, fmaf(-2.f, a0[gq * 4 + e], c));
      }
    }
    gmin[rt] = g;
    m = fminf(m, g);
  }
  m = fminf(m, __shfl_xor(m, 32));
  if (lane < 32) m_red[w][col] = m;
  __syncthreads();                                          // barrier 2

  // thr = min_w(m) + 2*B_t (redundant per-lane; no serial section).
  // B_t bounds |S_bf16 - S_f32| for RNE operands; certified rounds 6-18.
  float thr;
  {
    const float esq = ((esq_p[col * 8 + 0] + esq_p[col * 8 + 1]) +
                       (esq_p[col * 8 + 2] + esq_p[col * 8 + 3])) +
                      ((esq_p[col * 8 + 4] + esq_p[col * 8 + 5]) +
                       (esq_p[col * 8 + 6] + esq_p[col * 8 + 7]));
    const float mt = fminf(fminf(m_red[0][col], m_red[1][col]),
                           fminf(m_red[2][col], m_red[3][col]));
    thr = mt + 0.0328f * sqrtf(esq) + 2e-4f;
  }

  // ---- Pass B: bit-identical recompute of surviving tiles -> LDS lists ----
#pragma unroll
  for (int rt = 0; rt < 4; ++rt) {
    if (!__any(gmin[rt] <= thr)) continue;
    f32x16 a0 = {};
#pragma unroll
    for (int s = 0; s < 4; ++s) {
      const s16x8 Af = frag[((w * 4 + rt) * 4 + s) * 64 + lane];
      a0 = __builtin_amdgcn_mfma_f32_32x32x16_bf16(Af, Bf[s], a0, 0, 0, 0);
    }
    const int rb = rowbase + rt * 32 + 4 * half;
#pragma unroll
    for (int gq = 0; gq < 4; ++gq) {
      const float4 cs = *reinterpret_cast<const float4*>(&csq_l[rb + 8 * gq]);
#pragma unroll
      for (int e = 0; e < 4; ++e) {
        const float c = (e == 0) ? cs.x : (e == 1) ? cs.y : (e == 2) ? cs.z : cs.w;
        if (fmaf(-2.f, a0[gq * 4 + e], c) <= thr) {
          const int p = atomicAdd(&cnt[col], 1);
          if (p < CAP) list[col][p] = (short)(rb + 8 * gq + e);
        }
      }
    }
  }
  __syncthreads();                                          // barrier 3

  // ---- Phase C+D fused: rescore, then the group writes its own token ----
  {
    const int t = tid >> 3, sub = tid & 7;
    const int nc = cnt[t];
    const float* erow = ef32 + t * DIM + sub * 8;
    u64 bb = ~0ull;
    if (nc <= CAP) {
      for (int i = 0; i < nc; ++i)
        bb = u64min(bb, group_score8(cb, erow, csq_l, list[t][i], sub));
    } else {
      // overflow (adversarial data only): full exact scan, still correct
      for (int k = 0; k < KCB; ++k)
        bb = u64min(bb, group_score8(cb, erow, csq_l, k, sub));
    }
    // bb is uniform across the 8-lane group (shfl-reduced scores).
    const int idx = (int)(unsigned)(bb & 0xFFFFFFFFull);
    if (sub == 0)
      __builtin_nontemporal_store(
          (float)idx, &out[(size_t)2 * N_TOK * DIM + blk * TPB + t]);

    // gather-write both quantized sections: 2 float4/lane/section
    const f32x4* cbv = reinterpret_cast<const f32x4*>(cb + (size_t)idx * DIM);
    f32x4* out4 = reinterpret_cast<f32x4*>(out);
    const size_t base = (size_t)(blk * TPB + t) * (DIM / 4);
#pragma unroll
    for (int jj = 0; jj < 2; ++jj) {
      const int j = sub + 8 * jj;
      const f32x4 v = cbv[j];
      __builtin_nontemporal_store(v, &out4[base + j]);
      __builtin_nontemporal_store(v, &out4[(size_t)N_TOK * (DIM / 4) + base + j]);
    }
  }
}

extern "C" void kernel_launch(void* const* d_in, const int* in_sizes, int n_in,
                              void* d_out, int out_size, void* d_ws, size_t ws_size,
                              hipStream_t stream) {
  const float* cb  = (const float*)d_in[0];   // (512, 64) f32
  const float* emb = (const float*)d_in[1];   // (65536, 1, 64) f32
  float* out = (float*)d_out;
  uint4* cb_frag = (uint4*)d_ws;                               // 64 KB fragment-major bf16
  float* csqg = (float*)((char*)d_ws + (size_t)KCB * DIM * 2); // 2 KB csq

  vq_prep_kernel<<<18, 256, 0, stream>>>(cb, cb_frag, csqg);
  vq_argmin_kernel<<<N_TOK / TPB, 256, 0, stream>>>(cb, emb, cb_frag, csqg, out);
}